// Round 4
// baseline (611.085 us; speedup 1.0000x reference)
//
#include <hip/hip_runtime.h>
#include <hip/hip_bf16.h>
#include <math.h>

// GPT-OSS MoE block. Split-bf16 (hi/lo) MFMA path, BM=128 (expert weight
// panels fetched exactly once, ne<=128 w.h.p.), T14 register prefetch of the
// next K-step's global loads, __launch_bounds__(256,2) to pin 2 blocks/CU.
// B=512 H=1024 I=1024 E=32 K=4.
//
// ws layout (floats): t[512*1024] | a[2048*1024] | o[2048*1024] |
//   tok[32*512](int) | tke[2048](int) | tkw[2048] | cnt[32] | base[32]
//   ~18.9 MB

#define NB   512
#define NH   1024
#define NI   1024
#define NE   32
#define NK   4
#define N2I  2048
#define CAP  512

static constexpr float EPS   = 1e-5f;
static constexpr float ALPHA = 1.702f;
static constexpr float LIMIT = 7.0f;

typedef short bf16x8 __attribute__((ext_vector_type(8)));
typedef float f32x4  __attribute__((ext_vector_type(4)));

// fp32 -> (hi, lo) bf16 split. hi = trunc16(x); lo = trunc16(x - hi).
// Dropped lo*lo MFMA term -> ~2^-16 relative product error.
__device__ __forceinline__ short hi16(float x) {
    return (short)(__float_as_uint(x) >> 16);
}
__device__ __forceinline__ short lo16(float x) {
    unsigned hb = __float_as_uint(x) & 0xFFFF0000u;
    float r = x - __uint_as_float(hb);
    return (short)(__float_as_uint(r) >> 16);
}
__device__ __forceinline__ void cvt8r(float4 v0, float4 v1,
                                      bf16x8& hh, bf16x8& ll) {
    float f[8] = {v0.x, v0.y, v0.z, v0.w, v1.x, v1.y, v1.z, v1.w};
#pragma unroll
    for (int i = 0; i < 8; i++) { hh[i] = hi16(f[i]); ll[i] = lo16(f[i]); }
}

// ------------------------------------------- rmsnorm + gate + top4 + route
__global__ __launch_bounds__(256) void k_rms_gate(
    const float* __restrict__ x, const float* __restrict__ scale,
    const float* __restrict__ gw, const float* __restrict__ gb,
    float* __restrict__ t, int* __restrict__ cnt,
    int* __restrict__ tok, int* __restrict__ tke, float* __restrict__ tkw) {
    __shared__ float sh_t[NH];
    __shared__ float sh_red[4];
    __shared__ float sh_g[NE];
    const int b = blockIdx.x, tid = threadIdx.x;
    const int lane = tid & 63, wid = tid >> 6;

    float4 xv = reinterpret_cast<const float4*>(x + (size_t)b * NH)[tid];
    float ss = xv.x * xv.x + xv.y * xv.y + xv.z * xv.z + xv.w * xv.w;
#pragma unroll
    for (int o = 32; o >= 1; o >>= 1) ss += __shfl_down(ss, o);
    if (lane == 0) sh_red[wid] = ss;
    __syncthreads();
    const float tot = sh_red[0] + sh_red[1] + sh_red[2] + sh_red[3];
    const float r = rsqrtf(tot * (1.0f / NH) + EPS);
    float4 sv = reinterpret_cast<const float4*>(scale)[tid];
    float4 tv;
    tv.x = xv.x * r * sv.x; tv.y = xv.y * r * sv.y;
    tv.z = xv.z * r * sv.z; tv.w = xv.w * r * sv.w;
    reinterpret_cast<float4*>(sh_t)[tid] = tv;
    reinterpret_cast<float4*>(t + (size_t)b * NH)[tid] = tv;
    __syncthreads();

    // gate logits: wave `wid` handles experts wid*8 .. wid*8+7
#pragma unroll
    for (int q = 0; q < 8; q++) {
        const int e = wid * 8 + q;
        const float* __restrict__ w = gw + (size_t)e * NH;
        float p = 0.f;
#pragma unroll
        for (int i = 0; i < 16; i++) { int k = lane + 64 * i; p += sh_t[k] * w[k]; }
#pragma unroll
        for (int o = 32; o >= 1; o >>= 1) p += __shfl_down(p, o);
        if (lane == 0) sh_g[e] = p + gb[e];
    }
    __syncthreads();

    if (tid == 0) {
        float gv[NE];
#pragma unroll
        for (int e = 0; e < NE; e++) gv[e] = sh_g[e];
        float vals[NK]; int ids[NK];
#pragma unroll
        for (int k = 0; k < NK; k++) {          // strict > keeps lowest index
            int bi = 0; float bv = gv[0];
            for (int e = 1; e < NE; e++) if (gv[e] > bv) { bv = gv[e]; bi = e; }
            vals[k] = bv; ids[k] = bi; gv[bi] = -1e30f;
        }
        const float m = vals[0];
        float s = 0.f, wv[NK];
#pragma unroll
        for (int k = 0; k < NK; k++) { wv[k] = __expf(vals[k] - m); s += wv[k]; }
        const float inv = 1.f / s;
#pragma unroll
        for (int k = 0; k < NK; k++) {
            const int e = ids[k];
            const int pos = atomicAdd(&cnt[e], 1);
            tok[e * CAP + pos] = b;
            tke[b * NK + k] = (e << 16) | pos;
            tkw[b * NK + k] = wv[k] * inv;
        }
    }
}

// ---------------------------------------------------------------- prefix
__global__ void k_prefix(const int* __restrict__ cnt, int* __restrict__ base) {
    if (threadIdx.x == 0) {
        int r = 0;
        for (int e = 0; e < NE; e++) { base[e] = r; r += cnt[e]; }
    }
}

// ------------------------------------------------- expert GEMM 1 + swiglu
// block: expert e, 128 token rows (M), 128 h-cols (N), K=1024 in BK=64 steps.
// 4 waves in 2x2; each wave 64x64 = 4x4 frags of mfma_f32_16x16x32_bf16.
// Split-bf16: acc += Ah*Bh + Ah*Bl + Al*Bh. T14: global loads for step k+1
// issued before step k's MFMA phase; converted+ds_written next iteration.
__global__ __launch_bounds__(256, 2) void k_mlp1(
    const float* __restrict__ t, const float* __restrict__ w1,
    const float* __restrict__ b1, const int* __restrict__ cnt,
    const int* __restrict__ base, const int* __restrict__ tok,
    float* __restrict__ a) {
    const int e  = blockIdx.z;
    const int ne = cnt[e];
    const int m0 = blockIdx.y * 128;
    if (m0 >= ne) return;
    const int c0 = blockIdx.x * 128;
    const float* __restrict__ W = w1 + (size_t)e * N2I * NH + (size_t)c0 * NH;

    __shared__ short Ah[128][72], Al[128][72];   // +8 pad
    __shared__ short Bh[128][72], Bl[128][72];
    __shared__ int   toks[128];

    const int tid = threadIdx.x;
    if (tid < 128) toks[tid] = (m0 + tid < ne) ? tok[e * CAP + m0 + tid] : -1;
    __syncthreads();

    const int lane = tid & 63;
    const int wv   = tid >> 6;
    const int wr = wv >> 1, wc = wv & 1;
    const int frow = lane & 15;
    const int fk   = (lane >> 4) * 8;
    const int sr = tid >> 3;      // staging row 0..31
    const int sg = (tid & 7) * 8; // staging float-8 group offset

    f32x4 acc[4][4] = {};
    float4 ra[4][2], rb[4][2];
    int tkr[4];

    // prologue: load k0=0 into regs
#pragma unroll
    for (int p = 0; p < 4; p++) {
        const int r = sr + 32 * p;
        const int tk = toks[r]; tkr[p] = tk;
        const float* src = t + (size_t)(tk < 0 ? 0 : tk) * NH + sg;
        ra[p][0] = *(const float4*)src;
        ra[p][1] = *(const float4*)(src + 4);
        const float* wsrc = W + (size_t)r * NH + sg;
        rb[p][0] = *(const float4*)wsrc;
        rb[p][1] = *(const float4*)(wsrc + 4);
    }

    for (int k0 = 0; k0 < NH; k0 += 64) {
        // ---- convert + write step-k0 regs to LDS
#pragma unroll
        for (int p = 0; p < 4; p++) {
            const int r = sr + 32 * p;
            bf16x8 hh, ll;
            cvt8r(ra[p][0], ra[p][1], hh, ll);
            if (tkr[p] < 0) {
#pragma unroll
                for (int i = 0; i < 8; i++) { hh[i] = 0; ll[i] = 0; }
            }
            *(bf16x8*)&Ah[r][sg] = hh;
            *(bf16x8*)&Al[r][sg] = ll;
            cvt8r(rb[p][0], rb[p][1], hh, ll);
            *(bf16x8*)&Bh[r][sg] = hh;
            *(bf16x8*)&Bl[r][sg] = ll;
        }
        // ---- issue step-(k0+64) loads; they land during the MFMA phase
        if (k0 + 64 < NH) {
            const int kn = k0 + 64;
#pragma unroll
            for (int p = 0; p < 4; p++) {
                const int r = sr + 32 * p;
                const int tk = tkr[p];
                const float* src = t + (size_t)(tk < 0 ? 0 : tk) * NH + kn + sg;
                ra[p][0] = *(const float4*)src;
                ra[p][1] = *(const float4*)(src + 4);
                const float* wsrc = W + (size_t)r * NH + kn + sg;
                rb[p][0] = *(const float4*)wsrc;
                rb[p][1] = *(const float4*)(wsrc + 4);
            }
        }
        __syncthreads();
#pragma unroll
        for (int kk = 0; kk < 64; kk += 32) {
            bf16x8 ah[4], al[4], bh[4], bl[4];
#pragma unroll
            for (int m = 0; m < 4; m++) {
                const int r = wr * 64 + m * 16 + frow;
                ah[m] = *(const bf16x8*)&Ah[r][kk + fk];
                al[m] = *(const bf16x8*)&Al[r][kk + fk];
            }
#pragma unroll
            for (int n = 0; n < 4; n++) {
                const int c = wc * 64 + n * 16 + frow;
                bh[n] = *(const bf16x8*)&Bh[c][kk + fk];
                bl[n] = *(const bf16x8*)&Bl[c][kk + fk];
            }
#pragma unroll
            for (int m = 0; m < 4; m++)
#pragma unroll
                for (int n = 0; n < 4; n++) {
                    acc[m][n] = __builtin_amdgcn_mfma_f32_16x16x32_bf16(ah[m], bh[n], acc[m][n], 0, 0, 0);
                    acc[m][n] = __builtin_amdgcn_mfma_f32_16x16x32_bf16(ah[m], bl[n], acc[m][n], 0, 0, 0);
                    acc[m][n] = __builtin_amdgcn_mfma_f32_16x16x32_bf16(al[m], bh[n], acc[m][n], 0, 0, 0);
                }
        }
        __syncthreads();
    }

    // epilogue: bias + interleaved swiglu. col = lane&15 -> adjacent lanes
    // hold the (glu, lin) pair; shfl_xor(1) fetches the partner.
    const int slot0 = base[e];
#pragma unroll
    for (int m = 0; m < 4; m++)
#pragma unroll
        for (int n = 0; n < 4; n++) {
            const int gcol = c0 + wc * 64 + n * 16 + frow;
            const float bias = b1[e * N2I + gcol];
            f32x4 v = acc[m][n];
#pragma unroll
            for (int j = 0; j < 4; j++) {
                const float h  = v[j] + bias;
                const float hp = __shfl_xor(h, 1);   // partner col's value
                const int row = m0 + wr * 64 + m * 16 + (lane >> 4) * 4 + j;
                if (!(lane & 1) && row < ne) {
                    const float xg = fminf(h, LIMIT);
                    const float xl = fminf(fmaxf(hp, -LIMIT), LIMIT);
                    const float sg2 = 1.f / (1.f + __expf(-ALPHA * xg));
                    a[(size_t)(slot0 + row) * NI + (gcol >> 1)] = xg * sg2 * (xl + 1.f);
                }
            }
        }
}

// ------------------------------------------------- expert GEMM 2 (dense o)
__global__ __launch_bounds__(256, 2) void k_mlp2(
    const float* __restrict__ a, const float* __restrict__ w2,
    const float* __restrict__ b2, const int* __restrict__ cnt,
    const int* __restrict__ base, float* __restrict__ o) {
    const int e  = blockIdx.z;
    const int ne = cnt[e];
    const int m0 = blockIdx.y * 128;
    if (m0 >= ne) return;
    const int c0 = blockIdx.x * 128;
    const int slot0 = base[e];
    const float* __restrict__ W = w2 + (size_t)e * NH * NI + (size_t)c0 * NI;

    __shared__ short Ah[128][72], Al[128][72];
    __shared__ short Bh[128][72], Bl[128][72];

    const int tid = threadIdx.x;
    const int lane = tid & 63;
    const int wv   = tid >> 6;
    const int wr = wv >> 1, wc = wv & 1;
    const int frow = lane & 15;
    const int fk   = (lane >> 4) * 8;
    const int sr = tid >> 3;
    const int sg = (tid & 7) * 8;

    f32x4 acc[4][4] = {};
    float4 ra[4][2], rb[4][2];
    int mv[4];

    // prologue: load k0=0
#pragma unroll
    for (int p = 0; p < 4; p++) {
        const int r = sr + 32 * p;
        const int m = m0 + r;
        mv[p] = (m < ne);
        const float* src = a + (size_t)(mv[p] ? (slot0 + m) : 0) * NI + sg;
        ra[p][0] = *(const float4*)src;
        ra[p][1] = *(const float4*)(src + 4);
        const float* wsrc = W + (size_t)r * NI + sg;
        rb[p][0] = *(const float4*)wsrc;
        rb[p][1] = *(const float4*)(wsrc + 4);
    }

    for (int k0 = 0; k0 < NI; k0 += 64) {
#pragma unroll
        for (int p = 0; p < 4; p++) {
            const int r = sr + 32 * p;
            bf16x8 hh, ll;
            cvt8r(ra[p][0], ra[p][1], hh, ll);
            if (!mv[p]) {
#pragma unroll
                for (int i = 0; i < 8; i++) { hh[i] = 0; ll[i] = 0; }
            }
            *(bf16x8*)&Ah[r][sg] = hh;
            *(bf16x8*)&Al[r][sg] = ll;
            cvt8r(rb[p][0], rb[p][1], hh, ll);
            *(bf16x8*)&Bh[r][sg] = hh;
            *(bf16x8*)&Bl[r][sg] = ll;
        }
        if (k0 + 64 < NI) {
            const int kn = k0 + 64;
#pragma unroll
            for (int p = 0; p < 4; p++) {
                const int r = sr + 32 * p;
                const int m = m0 + r;
                const float* src = a + (size_t)(mv[p] ? (slot0 + m) : 0) * NI + kn + sg;
                ra[p][0] = *(const float4*)src;
                ra[p][1] = *(const float4*)(src + 4);
                const float* wsrc = W + (size_t)r * NI + kn + sg;
                rb[p][0] = *(const float4*)wsrc;
                rb[p][1] = *(const float4*)(wsrc + 4);
            }
        }
        __syncthreads();
#pragma unroll
        for (int kk = 0; kk < 64; kk += 32) {
            bf16x8 ah[4], al[4], bh[4], bl[4];
#pragma unroll
            for (int m = 0; m < 4; m++) {
                const int r = wr * 64 + m * 16 + frow;
                ah[m] = *(const bf16x8*)&Ah[r][kk + fk];
                al[m] = *(const bf16x8*)&Al[r][kk + fk];
            }
#pragma unroll
            for (int n = 0; n < 4; n++) {
                const int c = wc * 64 + n * 16 + frow;
                bh[n] = *(const bf16x8*)&Bh[c][kk + fk];
                bl[n] = *(const bf16x8*)&Bl[c][kk + fk];
            }
#pragma unroll
            for (int m = 0; m < 4; m++)
#pragma unroll
                for (int n = 0; n < 4; n++) {
                    acc[m][n] = __builtin_amdgcn_mfma_f32_16x16x32_bf16(ah[m], bh[n], acc[m][n], 0, 0, 0);
                    acc[m][n] = __builtin_amdgcn_mfma_f32_16x16x32_bf16(ah[m], bl[n], acc[m][n], 0, 0, 0);
                    acc[m][n] = __builtin_amdgcn_mfma_f32_16x16x32_bf16(al[m], bh[n], acc[m][n], 0, 0, 0);
                }
        }
        __syncthreads();
    }

#pragma unroll
    for (int m = 0; m < 4; m++)
#pragma unroll
        for (int n = 0; n < 4; n++) {
            const int gcol = c0 + wc * 64 + n * 16 + frow;
            const float bias = b2[e * NH + gcol];
            f32x4 v = acc[m][n];
#pragma unroll
            for (int j = 0; j < 4; j++) {
                const int row = m0 + wr * 64 + m * 16 + (lane >> 4) * 4 + j;
                if (row < ne)
                    o[(size_t)(slot0 + row) * NH + gcol] = v[j] + bias;
            }
        }
}

// ---------------------------------------------- combine: out = x + sum w*o
__global__ __launch_bounds__(256) void k_combine(
    const float* __restrict__ x, const float* __restrict__ o,
    const int* __restrict__ base, const int* __restrict__ tke,
    const float* __restrict__ tkw, float* __restrict__ out) {
    const int b = blockIdx.x, tid = threadIdx.x;
    int slots[NK]; float wk[NK];
#pragma unroll
    for (int k = 0; k < NK; k++) {
        const int v = tke[b * NK + k];
        slots[k] = base[v >> 16] + (v & 0xFFFF);
        wk[k] = tkw[b * NK + k];
    }
    float4 r = reinterpret_cast<const float4*>(x + (size_t)b * NH)[tid];
#pragma unroll
    for (int k = 0; k < NK; k++) {
        float4 ov = reinterpret_cast<const float4*>(o + (size_t)slots[k] * NH)[tid];
        r.x += wk[k] * ov.x; r.y += wk[k] * ov.y;
        r.z += wk[k] * ov.z; r.w += wk[k] * ov.w;
    }
    reinterpret_cast<float4*>(out + (size_t)b * NH)[tid] = r;
}

// ---------------------------------------------------------------- launch
extern "C" void kernel_launch(void* const* d_in, const int* in_sizes, int n_in,
                              void* d_out, int out_size, void* d_ws, size_t ws_size,
                              hipStream_t stream) {
    const float* x     = (const float*)d_in[0];
    const float* scale = (const float*)d_in[1];
    const float* gw    = (const float*)d_in[2];
    const float* gb    = (const float*)d_in[3];
    const float* w1    = (const float*)d_in[4];
    const float* b1    = (const float*)d_in[5];
    const float* w2    = (const float*)d_in[6];
    const float* b2    = (const float*)d_in[7];
    float* out = (float*)d_out;

    float* t   = (float*)d_ws;                         // 512*1024
    float* a   = t + (size_t)NB * NH;                  // 2048*1024
    float* o   = a + (size_t)NB * NK * NI;             // 2048*1024
    int*   tok = (int*)(o + (size_t)NB * NK * NH);     // 32*512
    int*   tke = tok + NE * CAP;                       // 512*4
    float* tkw = (float*)(tke + NB * NK);              // 512*4
    int*   cnt = (int*)(tkw + NB * NK);                // 32
    int*   bse = cnt + NE;                             // 32

    hipMemsetAsync(cnt, 0, NE * sizeof(int), stream);
    k_rms_gate<<<NB, 256, 0, stream>>>(x, scale, gw, gb, t, cnt, tok, tke, tkw);
    k_prefix<<<1, 64, 0, stream>>>(cnt, bse);
    k_mlp1<<<dim3(N2I / 128, NB / 128, NE), 256, 0, stream>>>(t, w1, b1, cnt, bse, tok, a);
    k_mlp2<<<dim3(NH / 128, NB / 128, NE), 256, 0, stream>>>(a, w2, b2, cnt, bse, o);
    k_combine<<<NB, 256, 0, stream>>>(x, o, bse, tke, tkw, out);
}

// Round 5
// 598.610 us; speedup vs baseline: 1.0208x; 1.0208x over previous
//
#include <hip/hip_runtime.h>
#include <hip/hip_bf16.h>
#include <math.h>

// GPT-OSS MoE block. Split-bf16 (hi/lo) MFMA path.
// R4 change: GEMMs restructured to 512-thread / 8-wave blocks, BK=32,
// wave tile 32x64, __launch_bounds__(512,2) -> VGPR<=128, 16 waves/CU.
// Theory: r3's 8 barrier-synced waves/CU stalled in lockstep on vmcnt(0);
// more independent waves + smaller per-step payload hides HBM latency.
// B=512 H=1024 I=1024 E=32 K=4.
//
// ws layout (floats): t[512*1024] | a[2048*1024] | o[2048*1024] |
//   tok[32*512](int) | tke[2048](int) | tkw[2048] | cnt[32] | base[32]

#define NB   512
#define NH   1024
#define NI   1024
#define NE   32
#define NK   4
#define N2I  2048
#define CAP  512
#define PADK 40   // BK=32 + 8 shorts pad (row stride 80 B -> <=2-way read conflict)

static constexpr float EPS   = 1e-5f;
static constexpr float ALPHA = 1.702f;
static constexpr float LIMIT = 7.0f;

typedef short bf16x8 __attribute__((ext_vector_type(8)));
typedef float f32x4  __attribute__((ext_vector_type(4)));

// fp32 -> (hi, lo) bf16 split. hi = trunc16(x); lo = trunc16(x - hi).
__device__ __forceinline__ short hi16(float x) {
    return (short)(__float_as_uint(x) >> 16);
}
__device__ __forceinline__ short lo16(float x) {
    unsigned hb = __float_as_uint(x) & 0xFFFF0000u;
    float r = x - __uint_as_float(hb);
    return (short)(__float_as_uint(r) >> 16);
}
__device__ __forceinline__ void cvt8r(float4 v0, float4 v1,
                                      bf16x8& hh, bf16x8& ll) {
    float f[8] = {v0.x, v0.y, v0.z, v0.w, v1.x, v1.y, v1.z, v1.w};
#pragma unroll
    for (int i = 0; i < 8; i++) { hh[i] = hi16(f[i]); ll[i] = lo16(f[i]); }
}

// ------------------------------------------- rmsnorm + gate + top4 + route
__global__ __launch_bounds__(256) void k_rms_gate(
    const float* __restrict__ x, const float* __restrict__ scale,
    const float* __restrict__ gw, const float* __restrict__ gb,
    float* __restrict__ t, int* __restrict__ cnt,
    int* __restrict__ tok, int* __restrict__ tke, float* __restrict__ tkw) {
    __shared__ float sh_t[NH];
    __shared__ float sh_red[4];
    __shared__ float sh_g[NE];
    const int b = blockIdx.x, tid = threadIdx.x;
    const int lane = tid & 63, wid = tid >> 6;

    float4 xv = reinterpret_cast<const float4*>(x + (size_t)b * NH)[tid];
    float ss = xv.x * xv.x + xv.y * xv.y + xv.z * xv.z + xv.w * xv.w;
#pragma unroll
    for (int o = 32; o >= 1; o >>= 1) ss += __shfl_down(ss, o);
    if (lane == 0) sh_red[wid] = ss;
    __syncthreads();
    const float tot = sh_red[0] + sh_red[1] + sh_red[2] + sh_red[3];
    const float r = rsqrtf(tot * (1.0f / NH) + EPS);
    float4 sv = reinterpret_cast<const float4*>(scale)[tid];
    float4 tv;
    tv.x = xv.x * r * sv.x; tv.y = xv.y * r * sv.y;
    tv.z = xv.z * r * sv.z; tv.w = xv.w * r * sv.w;
    reinterpret_cast<float4*>(sh_t)[tid] = tv;
    reinterpret_cast<float4*>(t + (size_t)b * NH)[tid] = tv;
    __syncthreads();

    // gate logits: wave `wid` handles experts wid*8 .. wid*8+7
#pragma unroll
    for (int q = 0; q < 8; q++) {
        const int e = wid * 8 + q;
        const float* __restrict__ w = gw + (size_t)e * NH;
        float p = 0.f;
#pragma unroll
        for (int i = 0; i < 16; i++) { int k = lane + 64 * i; p += sh_t[k] * w[k]; }
#pragma unroll
        for (int o = 32; o >= 1; o >>= 1) p += __shfl_down(p, o);
        if (lane == 0) sh_g[e] = p + gb[e];
    }
    __syncthreads();

    if (tid == 0) {
        float gv[NE];
#pragma unroll
        for (int e = 0; e < NE; e++) gv[e] = sh_g[e];
        float vals[NK]; int ids[NK];
#pragma unroll
        for (int k = 0; k < NK; k++) {          // strict > keeps lowest index
            int bi = 0; float bv = gv[0];
            for (int e = 1; e < NE; e++) if (gv[e] > bv) { bv = gv[e]; bi = e; }
            vals[k] = bv; ids[k] = bi; gv[bi] = -1e30f;
        }
        const float m = vals[0];
        float s = 0.f, wv[NK];
#pragma unroll
        for (int k = 0; k < NK; k++) { wv[k] = __expf(vals[k] - m); s += wv[k]; }
        const float inv = 1.f / s;
#pragma unroll
        for (int k = 0; k < NK; k++) {
            const int e = ids[k];
            const int pos = atomicAdd(&cnt[e], 1);
            tok[e * CAP + pos] = b;
            tke[b * NK + k] = (e << 16) | pos;
            tkw[b * NK + k] = wv[k] * inv;
        }
    }
}

// ---------------------------------------------------------------- prefix
__global__ void k_prefix(const int* __restrict__ cnt, int* __restrict__ base) {
    if (threadIdx.x == 0) {
        int r = 0;
        for (int e = 0; e < NE; e++) { base[e] = r; r += cnt[e]; }
    }
}

// ------------------------------------------------- expert GEMM 1 + swiglu
// block: 512 thr / 8 waves (4M x 2N), tile 128x128, BK=32.
// wave tile 32x64 = 2x4 frags of mfma_f32_16x16x32_bf16.
// Split-bf16: acc += Ah*Bh + Ah*Bl + Al*Bh. Register prefetch depth 1.
__global__ __launch_bounds__(512, 2) void k_mlp1(
    const float* __restrict__ t, const float* __restrict__ w1,
    const float* __restrict__ b1, const int* __restrict__ cnt,
    const int* __restrict__ base, const int* __restrict__ tok,
    float* __restrict__ a) {
    const int e  = blockIdx.z;
    const int ne = cnt[e];
    const int m0 = blockIdx.y * 128;
    if (m0 >= ne) return;
    const int c0 = blockIdx.x * 128;
    const float* __restrict__ W = w1 + (size_t)e * N2I * NH + (size_t)c0 * NH;

    __shared__ short Ah[128][PADK], Al[128][PADK];
    __shared__ short Bh[128][PADK], Bl[128][PADK];
    __shared__ int   toks[128];

    const int tid = threadIdx.x;
    if (tid < 128) toks[tid] = (m0 + tid < ne) ? tok[e * CAP + m0 + tid] : -1;
    __syncthreads();

    const int lane = tid & 63;
    const int wid  = tid >> 6;
    const int wr = wid >> 1, wc = wid & 1;       // 4M x 2N wave grid
    const int frow = lane & 15;
    const int fk   = (lane >> 4) * 8;
    const int srow = tid >> 2;                   // staging row 0..127
    const int sc8  = (tid & 3) * 8;              // staging 8-float granule

    f32x4 acc[2][4] = {};

    const int tka = toks[srow];
    const float* __restrict__ asrc = t + (size_t)(tka < 0 ? 0 : tka) * NH + sc8;
    const float* __restrict__ bsrc = W + (size_t)srow * NH + sc8;

    float4 ra0 = *(const float4*)(asrc);
    float4 ra1 = *(const float4*)(asrc + 4);
    float4 rb0 = *(const float4*)(bsrc);
    float4 rb1 = *(const float4*)(bsrc + 4);

    for (int k0 = 0; k0 < NH; k0 += 32) {
        // ---- convert + write step-k0 regs to LDS
        bf16x8 hh, ll;
        cvt8r(ra0, ra1, hh, ll);
        if (tka < 0) { hh = (bf16x8)(short)0; ll = (bf16x8)(short)0; }
        *(bf16x8*)&Ah[srow][sc8] = hh;
        *(bf16x8*)&Al[srow][sc8] = ll;
        cvt8r(rb0, rb1, hh, ll);
        *(bf16x8*)&Bh[srow][sc8] = hh;
        *(bf16x8*)&Bl[srow][sc8] = ll;
        // ---- issue step-(k0+32) loads; they land during the MFMA phase
        if (k0 + 32 < NH) {
            ra0 = *(const float4*)(asrc + k0 + 32);
            ra1 = *(const float4*)(asrc + k0 + 36);
            rb0 = *(const float4*)(bsrc + k0 + 32);
            rb1 = *(const float4*)(bsrc + k0 + 36);
        }
        __syncthreads();

        bf16x8 ah[2], al[2], bh[4], bl[4];
#pragma unroll
        for (int m = 0; m < 2; m++) {
            const int r = wr * 32 + m * 16 + frow;
            ah[m] = *(const bf16x8*)&Ah[r][fk];
            al[m] = *(const bf16x8*)&Al[r][fk];
        }
#pragma unroll
        for (int n = 0; n < 4; n++) {
            const int c = wc * 64 + n * 16 + frow;
            bh[n] = *(const bf16x8*)&Bh[c][fk];
            bl[n] = *(const bf16x8*)&Bl[c][fk];
        }
#pragma unroll
        for (int m = 0; m < 2; m++)
#pragma unroll
            for (int n = 0; n < 4; n++) {
                acc[m][n] = __builtin_amdgcn_mfma_f32_16x16x32_bf16(ah[m], bh[n], acc[m][n], 0, 0, 0);
                acc[m][n] = __builtin_amdgcn_mfma_f32_16x16x32_bf16(ah[m], bl[n], acc[m][n], 0, 0, 0);
                acc[m][n] = __builtin_amdgcn_mfma_f32_16x16x32_bf16(al[m], bh[n], acc[m][n], 0, 0, 0);
            }
        __syncthreads();
    }

    // epilogue: bias + interleaved swiglu. col = lane&15 -> adjacent lanes
    // hold the (glu, lin) pair; shfl_xor(1) fetches the partner.
    const int slot0 = base[e];
#pragma unroll
    for (int m = 0; m < 2; m++)
#pragma unroll
        for (int n = 0; n < 4; n++) {
            const int gcol = c0 + wc * 64 + n * 16 + frow;
            const float bias = b1[e * N2I + gcol];
            f32x4 v = acc[m][n];
#pragma unroll
            for (int j = 0; j < 4; j++) {
                const float h  = v[j] + bias;
                const float hp = __shfl_xor(h, 1);   // partner col's value
                const int row = m0 + wr * 32 + m * 16 + (lane >> 4) * 4 + j;
                if (!(lane & 1) && row < ne) {
                    const float xg = fminf(h, LIMIT);
                    const float xl = fminf(fmaxf(hp, -LIMIT), LIMIT);
                    const float sg2 = 1.f / (1.f + __expf(-ALPHA * xg));
                    a[(size_t)(slot0 + row) * NI + (gcol >> 1)] = xg * sg2 * (xl + 1.f);
                }
            }
        }
}

// ------------------------------------------------- expert GEMM 2 (dense o)
// same structure; A rows are contiguous slots (no gather).
__global__ __launch_bounds__(512, 2) void k_mlp2(
    const float* __restrict__ a, const float* __restrict__ w2,
    const float* __restrict__ b2, const int* __restrict__ cnt,
    const int* __restrict__ base, float* __restrict__ o) {
    const int e  = blockIdx.z;
    const int ne = cnt[e];
    const int m0 = blockIdx.y * 128;
    if (m0 >= ne) return;
    const int c0 = blockIdx.x * 128;
    const int slot0 = base[e];
    const float* __restrict__ W = w2 + (size_t)e * NH * NI + (size_t)c0 * NI;

    __shared__ short Ah[128][PADK], Al[128][PADK];
    __shared__ short Bh[128][PADK], Bl[128][PADK];

    const int tid = threadIdx.x;
    const int lane = tid & 63;
    const int wid  = tid >> 6;
    const int wr = wid >> 1, wc = wid & 1;
    const int frow = lane & 15;
    const int fk   = (lane >> 4) * 8;
    const int srow = tid >> 2;
    const int sc8  = (tid & 3) * 8;

    f32x4 acc[2][4] = {};

    const int mval = (m0 + srow < ne);
    const float* __restrict__ asrc =
        a + (size_t)(mval ? (slot0 + m0 + srow) : 0) * NI + sc8;
    const float* __restrict__ bsrc = W + (size_t)srow * NI + sc8;

    float4 ra0 = *(const float4*)(asrc);
    float4 ra1 = *(const float4*)(asrc + 4);
    float4 rb0 = *(const float4*)(bsrc);
    float4 rb1 = *(const float4*)(bsrc + 4);

    for (int k0 = 0; k0 < NI; k0 += 32) {
        bf16x8 hh, ll;
        cvt8r(ra0, ra1, hh, ll);
        if (!mval) { hh = (bf16x8)(short)0; ll = (bf16x8)(short)0; }
        *(bf16x8*)&Ah[srow][sc8] = hh;
        *(bf16x8*)&Al[srow][sc8] = ll;
        cvt8r(rb0, rb1, hh, ll);
        *(bf16x8*)&Bh[srow][sc8] = hh;
        *(bf16x8*)&Bl[srow][sc8] = ll;
        if (k0 + 32 < NI) {
            ra0 = *(const float4*)(asrc + k0 + 32);
            ra1 = *(const float4*)(asrc + k0 + 36);
            rb0 = *(const float4*)(bsrc + k0 + 32);
            rb1 = *(const float4*)(bsrc + k0 + 36);
        }
        __syncthreads();

        bf16x8 ah[2], al[2], bh[4], bl[4];
#pragma unroll
        for (int m = 0; m < 2; m++) {
            const int r = wr * 32 + m * 16 + frow;
            ah[m] = *(const bf16x8*)&Ah[r][fk];
            al[m] = *(const bf16x8*)&Al[r][fk];
        }
#pragma unroll
        for (int n = 0; n < 4; n++) {
            const int c = wc * 64 + n * 16 + frow;
            bh[n] = *(const bf16x8*)&Bh[c][fk];
            bl[n] = *(const bf16x8*)&Bl[c][fk];
        }
#pragma unroll
        for (int m = 0; m < 2; m++)
#pragma unroll
            for (int n = 0; n < 4; n++) {
                acc[m][n] = __builtin_amdgcn_mfma_f32_16x16x32_bf16(ah[m], bh[n], acc[m][n], 0, 0, 0);
                acc[m][n] = __builtin_amdgcn_mfma_f32_16x16x32_bf16(ah[m], bl[n], acc[m][n], 0, 0, 0);
                acc[m][n] = __builtin_amdgcn_mfma_f32_16x16x32_bf16(al[m], bh[n], acc[m][n], 0, 0, 0);
            }
        __syncthreads();
    }

#pragma unroll
    for (int m = 0; m < 2; m++)
#pragma unroll
        for (int n = 0; n < 4; n++) {
            const int gcol = c0 + wc * 64 + n * 16 + frow;
            const float bias = b2[e * NH + gcol];
            f32x4 v = acc[m][n];
#pragma unroll
            for (int j = 0; j < 4; j++) {
                const int row = m0 + wr * 32 + m * 16 + (lane >> 4) * 4 + j;
                if (row < ne)
                    o[(size_t)(slot0 + row) * NH + gcol] = v[j] + bias;
            }
        }
}

// ---------------------------------------------- combine: out = x + sum w*o
__global__ __launch_bounds__(256) void k_combine(
    const float* __restrict__ x, const float* __restrict__ o,
    const int* __restrict__ base, const int* __restrict__ tke,
    const float* __restrict__ tkw, float* __restrict__ out) {
    const int b = blockIdx.x, tid = threadIdx.x;
    int slots[NK]; float wk[NK];
#pragma unroll
    for (int k = 0; k < NK; k++) {
        const int v = tke[b * NK + k];
        slots[k] = base[v >> 16] + (v & 0xFFFF);
        wk[k] = tkw[b * NK + k];
    }
    float4 r = reinterpret_cast<const float4*>(x + (size_t)b * NH)[tid];
#pragma unroll
    for (int k = 0; k < NK; k++) {
        float4 ov = reinterpret_cast<const float4*>(o + (size_t)slots[k] * NH)[tid];
        r.x += wk[k] * ov.x; r.y += wk[k] * ov.y;
        r.z += wk[k] * ov.z; r.w += wk[k] * ov.w;
    }
    reinterpret_cast<float4*>(out + (size_t)b * NH)[tid] = r;
}

// ---------------------------------------------------------------- launch
extern "C" void kernel_launch(void* const* d_in, const int* in_sizes, int n_in,
                              void* d_out, int out_size, void* d_ws, size_t ws_size,
                              hipStream_t stream) {
    const float* x     = (const float*)d_in[0];
    const float* scale = (const float*)d_in[1];
    const float* gw    = (const float*)d_in[2];
    const float* gb    = (const float*)d_in[3];
    const float* w1    = (const float*)d_in[4];
    const float* b1    = (const float*)d_in[5];
    const float* w2    = (const float*)d_in[6];
    const float* b2    = (const float*)d_in[7];
    float* out = (float*)d_out;

    float* t   = (float*)d_ws;                         // 512*1024
    float* a   = t + (size_t)NB * NH;                  // 2048*1024
    float* o   = a + (size_t)NB * NK * NI;             // 2048*1024
    int*   tok = (int*)(o + (size_t)NB * NK * NH);     // 32*512
    int*   tke = tok + NE * CAP;                       // 512*4
    float* tkw = (float*)(tke + NB * NK);              // 512*4
    int*   cnt = (int*)(tkw + NB * NK);                // 32
    int*   bse = cnt + NE;                             // 32

    hipMemsetAsync(cnt, 0, NE * sizeof(int), stream);
    k_rms_gate<<<NB, 256, 0, stream>>>(x, scale, gw, gb, t, cnt, tok, tke, tkw);
    k_prefix<<<1, 64, 0, stream>>>(cnt, bse);
    k_mlp1<<<dim3(N2I / 128, NB / 128, NE), 512, 0, stream>>>(t, w1, b1, cnt, bse, tok, a);
    k_mlp2<<<dim3(NH / 128, NB / 128, NE), 512, 0, stream>>>(a, w2, b2, cnt, bse, o);
    k_combine<<<NB, 256, 0, stream>>>(x, o, bse, tke, tkw, out);
}

// Round 7
// 593.974 us; speedup vs baseline: 1.0288x; 1.0078x over previous
//
#include <hip/hip_runtime.h>
#include <hip/hip_bf16.h>
#include <math.h>

// GPT-OSS MoE block. Split-bf16 MFMA path, LDS-traffic-optimized.
// R7: wave tile 64x64 (4x4 frags 16x16x32), B operand hi-only (RNE) ->
// 2 MFMA passes (AhBh + AlBh), A split hi/lo. 4-wave 256-thr blocks,
// tile 128x128, BK=32, depth-2 register prefetch. Theory: R5 was
// LDS-throughput-bound (96+32 wave-ops/step/block at 12cyc = 164us/CU
// for mlp1); this cuts LDS ops ~1.8x and MFMA work 1.5x.
// B=512 H=1024 I=1024 E=32 K=4.

#define NB   512
#define NH   1024
#define NI   1024
#define NE   32
#define NK   4
#define N2I  2048
#define CAP  512
#define PADK 40   // 80B row stride: 16B-aligned, 2-way (free) bank aliasing

static constexpr float EPS   = 1e-5f;
static constexpr float ALPHA = 1.702f;
static constexpr float LIMIT = 7.0f;

typedef short bf16x8 __attribute__((ext_vector_type(8)));
typedef float f32x4  __attribute__((ext_vector_type(4)));

// fp32 -> (hi, lo) bf16 split (truncation; hi+lo exact to ~2^-16)
__device__ __forceinline__ short hi16(float x) {
    return (short)(__float_as_uint(x) >> 16);
}
__device__ __forceinline__ short lo16(float x) {
    unsigned hb = __float_as_uint(x) & 0xFFFF0000u;
    float r = x - __uint_as_float(hb);
    return (short)(__float_as_uint(r) >> 16);
}
// round-to-nearest-even bf16 for the hi-only operand (halves quant error)
__device__ __forceinline__ short rne16(float x) {
    unsigned u = __float_as_uint(x);
    return (short)((u + 0x7FFFu + ((u >> 16) & 1u)) >> 16);
}
__device__ __forceinline__ void cvtsplit8(float4 v0, float4 v1,
                                          bf16x8& hh, bf16x8& ll) {
    float f[8] = {v0.x, v0.y, v0.z, v0.w, v1.x, v1.y, v1.z, v1.w};
#pragma unroll
    for (int i = 0; i < 8; i++) { hh[i] = hi16(f[i]); ll[i] = lo16(f[i]); }
}
__device__ __forceinline__ void cvtrne8(float4 v0, float4 v1, bf16x8& hh) {
    float f[8] = {v0.x, v0.y, v0.z, v0.w, v1.x, v1.y, v1.z, v1.w};
#pragma unroll
    for (int i = 0; i < 8; i++) hh[i] = rne16(f[i]);
}

// ------------------------------------------- rmsnorm + gate + top4 + route
__global__ __launch_bounds__(256) void k_rms_gate(
    const float* __restrict__ x, const float* __restrict__ scale,
    const float* __restrict__ gw, const float* __restrict__ gb,
    float* __restrict__ t, int* __restrict__ cnt,
    int* __restrict__ tok, int* __restrict__ tke, float* __restrict__ tkw) {
    __shared__ float sh_t[NH];
    __shared__ float sh_red[4];
    __shared__ float sh_g[NE];
    const int b = blockIdx.x, tid = threadIdx.x;
    const int lane = tid & 63, wid = tid >> 6;

    float4 xv = reinterpret_cast<const float4*>(x + (size_t)b * NH)[tid];
    float ss = xv.x * xv.x + xv.y * xv.y + xv.z * xv.z + xv.w * xv.w;
#pragma unroll
    for (int o = 32; o >= 1; o >>= 1) ss += __shfl_down(ss, o);
    if (lane == 0) sh_red[wid] = ss;
    __syncthreads();
    const float tot = sh_red[0] + sh_red[1] + sh_red[2] + sh_red[3];
    const float r = rsqrtf(tot * (1.0f / NH) + EPS);
    float4 sv = reinterpret_cast<const float4*>(scale)[tid];
    float4 tv;
    tv.x = xv.x * r * sv.x; tv.y = xv.y * r * sv.y;
    tv.z = xv.z * r * sv.z; tv.w = xv.w * r * sv.w;
    reinterpret_cast<float4*>(sh_t)[tid] = tv;
    reinterpret_cast<float4*>(t + (size_t)b * NH)[tid] = tv;
    __syncthreads();

    // gate logits: wave `wid` handles experts wid*8 .. wid*8+7
#pragma unroll
    for (int q = 0; q < 8; q++) {
        const int e = wid * 8 + q;
        const float* __restrict__ w = gw + (size_t)e * NH;
        float p = 0.f;
#pragma unroll
        for (int i = 0; i < 16; i++) { int k = lane + 64 * i; p += sh_t[k] * w[k]; }
#pragma unroll
        for (int o = 32; o >= 1; o >>= 1) p += __shfl_down(p, o);
        if (lane == 0) sh_g[e] = p + gb[e];
    }
    __syncthreads();

    if (tid == 0) {
        float gv[NE];
#pragma unroll
        for (int e = 0; e < NE; e++) gv[e] = sh_g[e];
        float vals[NK]; int ids[NK];
#pragma unroll
        for (int k = 0; k < NK; k++) {          // strict > keeps lowest index
            int bi = 0; float bv = gv[0];
            for (int e = 1; e < NE; e++) if (gv[e] > bv) { bv = gv[e]; bi = e; }
            vals[k] = bv; ids[k] = bi; gv[bi] = -1e30f;
        }
        const float m = vals[0];
        float s = 0.f, wv[NK];
#pragma unroll
        for (int k = 0; k < NK; k++) { wv[k] = __expf(vals[k] - m); s += wv[k]; }
        const float inv = 1.f / s;
#pragma unroll
        for (int k = 0; k < NK; k++) {
            const int e = ids[k];
            const int pos = atomicAdd(&cnt[e], 1);
            tok[e * CAP + pos] = b;
            tke[b * NK + k] = (e << 16) | pos;
            tkw[b * NK + k] = wv[k] * inv;
        }
    }
}

// ---------------------------------------------------------------- prefix
__global__ void k_prefix(const int* __restrict__ cnt, int* __restrict__ base) {
    if (threadIdx.x == 0) {
        int r = 0;
        for (int e = 0; e < NE; e++) { base[e] = r; r += cnt[e]; }
    }
}

// load one depth buffer (A granules g0,g1 + B granules g0,g1) at k-offset k
#define LOADBUF(Aa, Ab, Ac, Ad, Ba, Bb, Bc, Bd, k)                           \
    do {                                                                     \
        Aa = *(const float4*)(asrc + (k));      Ab = *(const float4*)(asrc + (k) + 4);  \
        Ac = *(const float4*)(asrc + (k) + 16); Ad = *(const float4*)(asrc + (k) + 20); \
        Ba = *(const float4*)(bsrc + (k));      Bb = *(const float4*)(bsrc + (k) + 4);  \
        Bc = *(const float4*)(bsrc + (k) + 16); Bd = *(const float4*)(bsrc + (k) + 20); \
    } while (0)

// convert + store one depth buffer: A split hi/lo, B hi-only (RNE)
#define CVT_STORE(Aa, Ab, Ac, Ad, Ba, Bb, Bc, Bd)                            \
    do {                                                                     \
        bf16x8 hh, ll;                                                       \
        cvtsplit8(Aa, Ab, hh, ll);                                           \
        if (zA) { hh = (bf16x8)(short)0; ll = (bf16x8)(short)0; }            \
        *(bf16x8*)&Ah[srow][sh8] = hh;  *(bf16x8*)&Al[srow][sh8] = ll;       \
        cvtsplit8(Ac, Ad, hh, ll);                                           \
        if (zA) { hh = (bf16x8)(short)0; ll = (bf16x8)(short)0; }            \
        *(bf16x8*)&Ah[srow][sh8 + 16] = hh; *(bf16x8*)&Al[srow][sh8 + 16] = ll; \
        cvtrne8(Ba, Bb, hh);  *(bf16x8*)&Bh[srow][sh8] = hh;                 \
        cvtrne8(Bc, Bd, hh);  *(bf16x8*)&Bh[srow][sh8 + 16] = hh;            \
    } while (0)

// MFMA phase: 12 b128 frag reads -> 32 mfma (2 passes: AhBh + AlBh)
#define MFMA_PHASE()                                                         \
    do {                                                                     \
        bf16x8 ah[4], al[4], bh[4];                                          \
        _Pragma("unroll")                                                    \
        for (int m = 0; m < 4; m++) {                                        \
            const int r = wr * 64 + m * 16 + frow;                           \
            ah[m] = *(const bf16x8*)&Ah[r][fk];                              \
            al[m] = *(const bf16x8*)&Al[r][fk];                              \
        }                                                                    \
        _Pragma("unroll")                                                    \
        for (int n = 0; n < 4; n++) {                                        \
            const int c = wc * 64 + n * 16 + frow;                           \
            bh[n] = *(const bf16x8*)&Bh[c][fk];                              \
        }                                                                    \
        _Pragma("unroll")                                                    \
        for (int m = 0; m < 4; m++)                                          \
            _Pragma("unroll")                                                \
            for (int n = 0; n < 4; n++) {                                    \
                acc[m][n] = __builtin_amdgcn_mfma_f32_16x16x32_bf16(ah[m], bh[n], acc[m][n], 0, 0, 0); \
                acc[m][n] = __builtin_amdgcn_mfma_f32_16x16x32_bf16(al[m], bh[n], acc[m][n], 0, 0, 0); \
            }                                                                \
    } while (0)

// ------------------------------------------------- expert GEMM 1 + swiglu
// 256 thr / 4 waves (2M x 2N), block tile 128x128, wave tile 64x64, BK=32.
__global__ __launch_bounds__(256, 2) void k_mlp1(
    const float* __restrict__ t, const float* __restrict__ w1,
    const float* __restrict__ b1, const int* __restrict__ cnt,
    const int* __restrict__ base, const int* __restrict__ tok,
    float* __restrict__ a) {
    const int e  = blockIdx.z;
    const int ne = cnt[e];
    const int m0 = blockIdx.y * 128;
    if (m0 >= ne) return;
    const int c0 = blockIdx.x * 128;
    const float* __restrict__ W = w1 + (size_t)e * N2I * NH + (size_t)c0 * NH;

    __shared__ short Ah[128][PADK], Al[128][PADK], Bh[128][PADK];
    __shared__ int   toks[128];

    const int tid = threadIdx.x;
    if (tid < 128) toks[tid] = (m0 + tid < ne) ? tok[e * CAP + m0 + tid] : -1;
    __syncthreads();

    const int lane = tid & 63;
    const int wid  = tid >> 6;
    const int wr = wid >> 1, wc = wid & 1;       // 2M x 2N wave grid
    const int frow = lane & 15;
    const int fk   = (lane >> 4) * 8;
    const int srow = tid >> 1;                   // staging row 0..127
    const int sh8  = (tid & 1) * 8;              // granules at sh8, sh8+16

    f32x4 acc[4][4] = {};

    const int tka = toks[srow];
    const bool zA = (tka < 0);
    const float* __restrict__ asrc = t + (size_t)(zA ? 0 : tka) * NH + sh8;
    const float* __restrict__ bsrc = W + (size_t)srow * NH + sh8;

    float4 A0a, A0b, A0c, A0d, B0a, B0b, B0c, B0d;
    float4 A1a, A1b, A1c, A1d, B1a, B1b, B1c, B1d;
    LOADBUF(A0a, A0b, A0c, A0d, B0a, B0b, B0c, B0d, 0);
    LOADBUF(A1a, A1b, A1c, A1d, B1a, B1b, B1c, B1d, 32);

    for (int k0 = 0; k0 < NH; k0 += 64) {
        CVT_STORE(A0a, A0b, A0c, A0d, B0a, B0b, B0c, B0d);
        if (k0 + 64 < NH)
            LOADBUF(A0a, A0b, A0c, A0d, B0a, B0b, B0c, B0d, k0 + 64);
        __syncthreads();
        MFMA_PHASE();
        __syncthreads();
        CVT_STORE(A1a, A1b, A1c, A1d, B1a, B1b, B1c, B1d);
        if (k0 + 96 < NH)
            LOADBUF(A1a, A1b, A1c, A1d, B1a, B1b, B1c, B1d, k0 + 96);
        __syncthreads();
        MFMA_PHASE();
        __syncthreads();
    }

    // epilogue: bias + interleaved swiglu; adjacent lanes hold (glu,lin) pair
    const int slot0 = base[e];
#pragma unroll
    for (int m = 0; m < 4; m++)
#pragma unroll
        for (int n = 0; n < 4; n++) {
            const int gcol = c0 + wc * 64 + n * 16 + frow;
            const float bias = b1[e * N2I + gcol];
            f32x4 v = acc[m][n];
#pragma unroll
            for (int j = 0; j < 4; j++) {
                const float h  = v[j] + bias;
                const float hp = __shfl_xor(h, 1);   // partner col's value
                const int row = m0 + wr * 64 + m * 16 + (lane >> 4) * 4 + j;
                if (!(lane & 1) && row < ne) {
                    const float xg = fminf(h, LIMIT);
                    const float xl = fminf(fmaxf(hp, -LIMIT), LIMIT);
                    const float sg2 = 1.f / (1.f + __expf(-ALPHA * xg));
                    a[(size_t)(slot0 + row) * NI + (gcol >> 1)] = xg * sg2 * (xl + 1.f);
                }
            }
        }
}

// ------------------------------------------------- expert GEMM 2 (dense o)
__global__ __launch_bounds__(256, 2) void k_mlp2(
    const float* __restrict__ a, const float* __restrict__ w2,
    const float* __restrict__ b2, const int* __restrict__ cnt,
    const int* __restrict__ base, float* __restrict__ o) {
    const int e  = blockIdx.z;
    const int ne = cnt[e];
    const int m0 = blockIdx.y * 128;
    if (m0 >= ne) return;
    const int c0 = blockIdx.x * 128;
    const int slot0 = base[e];
    const float* __restrict__ W = w2 + (size_t)e * NH * NI + (size_t)c0 * NI;

    __shared__ short Ah[128][PADK], Al[128][PADK], Bh[128][PADK];

    const int tid = threadIdx.x;
    const int lane = tid & 63;
    const int wid  = tid >> 6;
    const int wr = wid >> 1, wc = wid & 1;
    const int frow = lane & 15;
    const int fk   = (lane >> 4) * 8;
    const int srow = tid >> 1;
    const int sh8  = (tid & 1) * 8;

    f32x4 acc[4][4] = {};

    const bool zA = (m0 + srow >= ne);
    const float* __restrict__ asrc =
        a + (size_t)(zA ? 0 : (slot0 + m0 + srow)) * NI + sh8;
    const float* __restrict__ bsrc = W + (size_t)srow * NI + sh8;

    float4 A0a, A0b, A0c, A0d, B0a, B0b, B0c, B0d;
    float4 A1a, A1b, A1c, A1d, B1a, B1b, B1c, B1d;
    LOADBUF(A0a, A0b, A0c, A0d, B0a, B0b, B0c, B0d, 0);
    LOADBUF(A1a, A1b, A1c, A1d, B1a, B1b, B1c, B1d, 32);

    for (int k0 = 0; k0 < NI; k0 += 64) {
        CVT_STORE(A0a, A0b, A0c, A0d, B0a, B0b, B0c, B0d);
        if (k0 + 64 < NI)
            LOADBUF(A0a, A0b, A0c, A0d, B0a, B0b, B0c, B0d, k0 + 64);
        __syncthreads();
        MFMA_PHASE();
        __syncthreads();
        CVT_STORE(A1a, A1b, A1c, A1d, B1a, B1b, B1c, B1d);
        if (k0 + 96 < NI)
            LOADBUF(A1a, A1b, A1c, A1d, B1a, B1b, B1c, B1d, k0 + 96);
        __syncthreads();
        MFMA_PHASE();
        __syncthreads();
    }

#pragma unroll
    for (int m = 0; m < 4; m++)
#pragma unroll
        for (int n = 0; n < 4; n++) {
            const int gcol = c0 + wc * 64 + n * 16 + frow;
            const float bias = b2[e * NH + gcol];
            f32x4 v = acc[m][n];
#pragma unroll
            for (int j = 0; j < 4; j++) {
                const int row = m0 + wr * 64 + m * 16 + (lane >> 4) * 4 + j;
                if (row < ne)
                    o[(size_t)(slot0 + row) * NH + gcol] = v[j] + bias;
            }
        }
}

// ---------------------------------------------- combine: out = x + sum w*o
__global__ __launch_bounds__(256) void k_combine(
    const float* __restrict__ x, const float* __restrict__ o,
    const int* __restrict__ base, const int* __restrict__ tke,
    const float* __restrict__ tkw, float* __restrict__ out) {
    const int b = blockIdx.x, tid = threadIdx.x;
    int slots[NK]; float wk[NK];
#pragma unroll
    for (int k = 0; k < NK; k++) {
        const int v = tke[b * NK + k];
        slots[k] = base[v >> 16] + (v & 0xFFFF);
        wk[k] = tkw[b * NK + k];
    }
    float4 r = reinterpret_cast<const float4*>(x + (size_t)b * NH)[tid];
#pragma unroll
    for (int k = 0; k < NK; k++) {
        float4 ov = reinterpret_cast<const float4*>(o + (size_t)slots[k] * NH)[tid];
        r.x += wk[k] * ov.x; r.y += wk[k] * ov.y;
        r.z += wk[k] * ov.z; r.w += wk[k] * ov.w;
    }
    reinterpret_cast<float4*>(out + (size_t)b * NH)[tid] = r;
}

// ---------------------------------------------------------------- launch
extern "C" void kernel_launch(void* const* d_in, const int* in_sizes, int n_in,
                              void* d_out, int out_size, void* d_ws, size_t ws_size,
                              hipStream_t stream) {
    const float* x     = (const float*)d_in[0];
    const float* scale = (const float*)d_in[1];
    const float* gw    = (const float*)d_in[2];
    const float* gb    = (const float*)d_in[3];
    const float* w1    = (const float*)d_in[4];
    const float* b1    = (const float*)d_in[5];
    const float* w2    = (const float*)d_in[6];
    const float* b2    = (const float*)d_in[7];
    float* out = (float*)d_out;

    float* t   = (float*)d_ws;                         // 512*1024
    float* a   = t + (size_t)NB * NH;                  // 2048*1024
    float* o   = a + (size_t)NB * NK * NI;             // 2048*1024
    int*   tok = (int*)(o + (size_t)NB * NK * NH);     // 32*512
    int*   tke = tok + NE * CAP;                       // 512*4
    float* tkw = (float*)(tke + NB * NK);              // 512*4
    int*   cnt = (int*)(tkw + NB * NK);                // 32
    int*   bse = cnt + NE;                             // 32

    hipMemsetAsync(cnt, 0, NE * sizeof(int), stream);
    k_rms_gate<<<NB, 256, 0, stream>>>(x, scale, gw, gb, t, cnt, tok, tke, tkw);
    k_prefix<<<1, 64, 0, stream>>>(cnt, bse);
    k_mlp1<<<dim3(N2I / 128, NB / 128, NE), 256, 0, stream>>>(t, w1, b1, cnt, bse, tok, a);
    k_mlp2<<<dim3(NH / 128, NB / 128, NE), 256, 0, stream>>>(a, w2, b2, cnt, bse, o);
    k_combine<<<NB, 256, 0, stream>>>(x, o, bse, tke, tkw, out);
}